// Round 3
// baseline (21456.195 us; speedup 1.0000x reference)
//
#include <hip/hip_runtime.h>

#define NT 512
#define ND 256
#define NH 1024
#define NB 64

// 16-lane row reduction at VALU rate via DPP row_ror (no LDS, no lgkm chains).
template<int CTRL>
__device__ __forceinline__ float dppadd(float v) {
  int x = __builtin_amdgcn_update_dpp(0, __builtin_bit_cast(int, v), CTRL, 0xf, 0xf, true);
  return v + __builtin_bit_cast(float, x);
}
__device__ __forceinline__ float rowsum16(float v) {
  v = dppadd<0x128>(v);   // row_ror:8
  v = dppadd<0x124>(v);   // row_ror:4
  v = dppadd<0x122>(v);   // row_ror:2
  v = dppadd<0x121>(v);   // row_ror:1
  return v;               // all 16 lanes of each row hold the row sum
}

// Grid: 256 wgs = 8 batch-groups x 32 H-slices. Block: 256 = 4 waves.
// Wave w owns rows w*8..w*8+7 of its 32-row slice; lane kc covers k-slice
// {kc*4 + j*256}. Output assignment: lane kc -> (batch kc>>3, row w*8+(kc&7)).
// Cross-wg h handoff at LLC scope (sc0 sc1), no agent fences.
__global__ void __launch_bounds__(256, 1)
rnn_step_kernel(const float* __restrict__ x,
                const float* __restrict__ Wx_w,
                const float* __restrict__ Wx_b,
                const float* __restrict__ Wh_w,
                const float* __restrict__ Ws_w,
                const float* __restrict__ Ws_b,
                const float* __restrict__ Us_w,
                float* __restrict__ out,
                float* __restrict__ hbuf,
                unsigned int* __restrict__ flags)
{
  const int tid = (int)threadIdx.x;
  const int w   = tid >> 6;
  const int kc  = tid & 63;
  const int s16 = kc & 15;          // lane within 16-row
  const int sl  = (int)blockIdx.x & 31;
  const int bg  = (int)blockIdx.x >> 5;
  const int r_base = sl * 32;
  const int b_base = bg * 8;
  const int b_out  = kc >> 3;       // this lane's output batch
  const int i_out  = kc & 7;        // this lane's output row (within wave)
  const int rg_out = r_base + w*8 + i_out;

  __shared__ float h_lds[8][NH];       // 32 KB
  __shared__ float x_lds[8][ND];       // 8 KB
  __shared__ float part[4][4][40];     // 2.5 KB: [wave][row16][36 slots + pad]

  // ---- weights in registers for all 512 steps ----
  float4 wh[8][4];
  float4 wx4[8];
  #pragma unroll
  for (int i = 0; i < 8; ++i) {
    const int rg = r_base + w*8 + i;
    #pragma unroll
    for (int j = 0; j < 4; ++j)
      wh[i][j] = *(const float4*)(Wh_w + (size_t)rg*NH + (kc*4 + j*256));
    wx4[i] = *(const float4*)(Wx_w + (size_t)rg*ND + kc*4);
  }
  float4 us4[4];
  #pragma unroll
  for (int j = 0; j < 4; ++j) us4[j] = *(const float4*)(Us_w + kc*4 + j*256);
  const float4 ws4 = *(const float4*)(Ws_w + kc*4);
  const float wsb  = Ws_b[0];
  // per-lane output-row constants (replaces LDS tables)
  const float wxb_r = Wx_b[rg_out];
  const float whd_r = Wh_w[(size_t)rg_out*NH + rg_out];
  const float usr_r = Us_w[rg_out];

  float* const hs_o = out + (size_t)NB*NT;
  float* const g_o  = hs_o + (size_t)NB*NT*NH;
  float* const l_o  = g_o  + (size_t)NB*NT*NH;
  float* const r_o  = l_o  + (size_t)NB*NT*NH;

  float myh = 0.f;   // this lane's own h_prev (register, not memory)

  for (int t = 0; t < NT; ++t) {
    // ---- stage x_t ----
    #pragma unroll
    for (int i = 0; i < 2; ++i) {
      const int f4 = tid + i*256;
      const int bb = f4 >> 6;
      const int d4 = f4 & 63;
      *(float4*)(&x_lds[bb][d4*4]) =
        *(const float4*)(x + ((size_t)(b_base+bb)*NT + t)*ND + d4*4);
    }
    __syncthreads();

    // ---- x-part FMAs into acc (before the recurrence wait) ----
    float acc[8][9];
    #pragma unroll
    for (int b = 0; b < 8; ++b) {
      const float4 x4 = *(const float4*)(&x_lds[b][kc*4]);
      #pragma unroll
      for (int i = 0; i < 8; ++i)
        acc[b][i] = wx4[i].x*x4.x + wx4[i].y*x4.y + wx4[i].z*x4.z + wx4[i].w*x4.w;
      acc[b][8] = ws4.x*x4.x + ws4.y*x4.y + ws4.z*x4.z + ws4.w*x4.w;
    }

    // ---- wait for h_{t-1} (LLC poll), stage it, h-part FMAs ----
    if (t > 0) {
      if (w == 0) {
        const unsigned int* fp = flags + ((size_t)bg*NT + (t-1))*32 + (kc & 31);
        while (true) {
          unsigned int v;
          asm volatile("global_load_dword %0, %1, off sc0 sc1\n\t"
                       "s_waitcnt vmcnt(0)"
                       : "=v"(v) : "v"(fp) : "memory");
          if (__all((int)(v != 0u))) break;
          __builtin_amdgcn_s_sleep(1);
        }
      }
      __syncthreads();
      const float* src = hbuf + ((size_t)((t-1)&1)*NB + b_base)*NH;
      float4 hv[8];
      #pragma unroll
      for (int i = 0; i < 8; ++i) {
        const float* a = src + (size_t)(tid + i*256)*4;
        asm volatile("global_load_dwordx4 %0, %1, off sc0 sc1"
                     : "=v"(hv[i]) : "v"(a) : "memory");
      }
      asm volatile("s_waitcnt vmcnt(0)" ::: "memory");
      __builtin_amdgcn_sched_barrier(0);
      #pragma unroll
      for (int i = 0; i < 8; ++i)
        *(float4*)((float*)h_lds + (size_t)(tid + i*256)*4) = hv[i];
      __syncthreads();

      #pragma unroll
      for (int j = 0; j < 4; ++j) {
        #pragma unroll
        for (int b = 0; b < 8; ++b) {
          const float4 h4 = *(const float4*)(&h_lds[b][kc*4 + j*256]);
          #pragma unroll
          for (int i = 0; i < 8; ++i)
            acc[b][i] += wh[i][j].x*h4.x + wh[i][j].y*h4.y +
                         wh[i][j].z*h4.z + wh[i][j].w*h4.w;
          acc[b][8] += us4[j].x*h4.x + us4[j].y*h4.y + us4[j].z*h4.z + us4[j].w*h4.w;
        }
      }
    }

    // ---- reduction: DPP rowsum16 + cross-row via tiny LDS, 2 phases ----
    float rowv = 0.f, gv = 0.f;
    #pragma unroll
    for (int P = 0; P < 2; ++P) {
      #pragma unroll
      for (int bb = 0; bb < 4; ++bb) {
        #pragma unroll
        for (int i = 0; i < 9; ++i) {
          const float v = rowsum16(acc[P*4 + bb][i]);
          const int sid = (i < 8) ? (bb*8 + i) : (32 + bb);
          if (s16 == (sid & 15)) part[w][kc >> 4][sid] = v;   // 1 owner lane/row
        }
      }
      asm volatile("s_waitcnt lgkmcnt(0)" ::: "memory");
      {
        const int myslot = kc & 31;
        const float sum = part[w][0][myslot] + part[w][1][myslot] +
                          part[w][2][myslot] + part[w][3][myslot];
        if ((kc < 32) == (P == 0)) rowv = sum;
        const int gl = P*4;                  // gate owner lanes [gl, gl+4)
        if (kc >= gl && kc < gl + 4) {
          const int gs_ = 32 + (kc - gl);
          gv = part[w][0][gs_] + part[w][1][gs_] +
               part[w][2][gs_] + part[w][3][gs_];
        }
      }
      asm volatile("s_waitcnt lgkmcnt(0)" ::: "memory");
    }

    // ---- epilogue: one (batch,row) output per lane ----
    const float gs_all = __shfl(gv, b_out, 64);   // gate pre-act of my batch
    const float sg   = 1.f / (1.f + expf(-(gs_all + wsb)));
    const float pre  = rowv + wxb_r;
    const float htld = tanhf(pre);
    const float hp   = myh;
    const float h    = (1.f - sg)*hp + sg*htld;
    myh = h;
    {
      float* hptr = hbuf + ((size_t)(t & 1)*NB + (b_base + b_out))*NH + rg_out;
      asm volatile("global_store_dword %0, %1, off sc0 sc1"
                   :: "v"(hptr), "v"(h) : "memory");
    }
    __syncthreads();     // drains vmcnt(0): all h stores at LLC before flag
    if (tid == 0) {
      unsigned int one = 1u;
      unsigned int* fp = flags + ((size_t)bg*NT + t)*32 + sl;
      asm volatile("global_store_dword %0, %1, off sc0 sc1"
                   :: "v"(fp), "v"(one) : "memory");
    }

    // ---- outputs (post-signal, off critical path) ----
    {
      const size_t obase = ((size_t)(b_base + b_out)*NT + t)*NH + rg_out;
      const float sp = sg * (1.f - sg);
      __builtin_nontemporal_store(h, &hs_o[obase]);
      __builtin_nontemporal_store(sg, &g_o[obase]);
      __builtin_nontemporal_store(1.f - sg, &l_o[obase]);
      __builtin_nontemporal_store((htld - hp)*(sp*usr_r) + sg*(1.f - htld*htld)*whd_r,
                                  &r_o[obase]);
    }
  }
}

// ys[b,t] = out_w . hs[b,t,:] + out_b
__global__ void yfinish_kernel(const float* __restrict__ hs,
                               const float* __restrict__ out_w,
                               const float* __restrict__ out_b,
                               float* __restrict__ ys)
{
  const int row  = (int)blockIdx.x*4 + ((int)threadIdx.x >> 6);
  const int lane = (int)threadIdx.x & 63;
  const float4* hp = (const float4*)(hs + (size_t)row*NH);
  const float4* wp = (const float4*)out_w;
  float s = 0.f;
  #pragma unroll
  for (int i = 0; i < 4; ++i) {
    const float4 h4 = hp[i*64 + lane];
    const float4 w4 = wp[i*64 + lane];
    s += h4.x*w4.x + h4.y*w4.y + h4.z*w4.z + h4.w*w4.w;
  }
  #pragma unroll
  for (int off = 32; off > 0; off >>= 1) s += __shfl_xor(s, off, 64);
  if (lane == 0) ys[row] = s + out_b[0];
}

extern "C" void kernel_launch(void* const* d_in, const int* in_sizes, int n_in,
                              void* d_out, int out_size, void* d_ws, size_t ws_size,
                              hipStream_t stream)
{
  (void)in_sizes; (void)n_in; (void)out_size; (void)ws_size;
  const float* x     = (const float*)d_in[0];
  const float* Wx_w  = (const float*)d_in[1];
  const float* Wx_b  = (const float*)d_in[2];
  const float* Wh_w  = (const float*)d_in[3];
  const float* Ws_w  = (const float*)d_in[4];
  const float* Ws_b  = (const float*)d_in[5];
  const float* Us_w  = (const float*)d_in[6];
  const float* out_w = (const float*)d_in[7];
  const float* out_b = (const float*)d_in[8];
  float* out = (float*)d_out;

  char* ws = (char*)d_ws;
  float* hbuf = (float*)ws;                                      // 512 KB
  unsigned int* flags = (unsigned int*)(ws + (size_t)2*NB*NH*4); // 512 KB

  hipMemsetAsync(flags, 0, (size_t)8*NT*32*sizeof(unsigned int), stream);
  rnn_step_kernel<<<dim3(256), dim3(256), 0, stream>>>(
      x, Wx_w, Wx_b, Wh_w, Ws_w, Ws_b, Us_w, out, hbuf, flags);
  yfinish_kernel<<<dim3((NB*NT)/4), dim3(256), 0, stream>>>(
      out + (size_t)NB*NT, out_w, out_b, out);
}

// Round 4
// 3687.566 us; speedup vs baseline: 5.8185x; 5.8185x over previous
//
#include <hip/hip_runtime.h>

#define NT 512
#define ND 256
#define NH 1024
#define NB 64

// 16-lane reduction at VALU rate via DPP row_ror (verified correct in R3).
template<int CTRL>
__device__ __forceinline__ float dppadd(float v) {
  int x = __builtin_amdgcn_update_dpp(0, __builtin_bit_cast(int, v), CTRL, 0xf, 0xf, true);
  return v + __builtin_bit_cast(float, x);
}
__device__ __forceinline__ float rowsum16(float v) {
  v = dppadd<0x128>(v);   // row_ror:8
  v = dppadd<0x124>(v);   // row_ror:4
  v = dppadd<0x122>(v);   // row_ror:2
  v = dppadd<0x121>(v);   // row_ror:1
  return v;               // all 16 lanes of the row hold the 16-lane sum
}
__device__ __forceinline__ float xor_combine(float v) {
  v += __shfl_xor(v, 16, 64);
  v += __shfl_xor(v, 32, 64);
  return v;               // all 64 lanes hold the full-wave sum
}

// Grid: 256 wgs = 8 batch-groups x 32 H-slices. Block: 256 = 4 waves.
// Wave w owns rows w*8..w*8+7 of its 32-row slice; lane kc covers k-slice
// {kc*4 + j*256 + m}. Output: lane kc -> (batch kc>>3, row w*8+(kc&7)).
// Cross-wg h handoff at LLC scope (sc0 sc1), no agent fences (R2-proven).
// NOTHING persists across the flag-wait except 2 scalars (rowv, gv) -> no
// spills (R3 lesson: 256 arch-VGPR cap, acc[8][9] spilled -> 26 GB scratch).
__global__ void __launch_bounds__(256, 1)
rnn_step_kernel(const float* __restrict__ x,
                const float* __restrict__ Wx_w,
                const float* __restrict__ Wx_b,
                const float* __restrict__ Wh_w,
                const float* __restrict__ Ws_w,
                const float* __restrict__ Ws_b,
                const float* __restrict__ Us_w,
                float* __restrict__ out,
                float* __restrict__ hbuf,
                unsigned int* __restrict__ flags)
{
  const int tid = (int)threadIdx.x;
  const int w   = tid >> 6;
  const int kc  = tid & 63;
  const int sl  = (int)blockIdx.x & 31;
  const int bg  = (int)blockIdx.x >> 5;
  const int r_base = sl * 32;
  const int b_base = bg * 8;
  const int b_out  = kc >> 3;       // this lane's output batch
  const int i_out  = kc & 7;        // this lane's output row (within wave)
  const int rg_out = r_base + w*8 + i_out;

  __shared__ float h_lds[8][NH];       // 32 KB
  __shared__ float x_lds[8][ND];       // 8 KB

  // ---- weights (compiler may cache in regs or re-load from L2; both ok) ----
  float4 wh[8][4];
  float4 wx4[8];
  #pragma unroll
  for (int i = 0; i < 8; ++i) {
    const int rg = r_base + w*8 + i;
    #pragma unroll
    for (int j = 0; j < 4; ++j)
      wh[i][j] = *(const float4*)(Wh_w + (size_t)rg*NH + (kc*4 + j*256));
    wx4[i] = *(const float4*)(Wx_w + (size_t)rg*ND + kc*4);
  }
  float4 us4[4];
  #pragma unroll
  for (int j = 0; j < 4; ++j) us4[j] = *(const float4*)(Us_w + kc*4 + j*256);
  const float4 ws4 = *(const float4*)(Ws_w + kc*4);
  const float wsb  = Ws_b[0];
  const float wxb_r = Wx_b[rg_out];
  const float whd_r = Wh_w[(size_t)rg_out*NH + rg_out];
  const float usr_r = Us_w[rg_out];

  float* const hs_o = out + (size_t)NB*NT;
  float* const g_o  = hs_o + (size_t)NB*NT*NH;
  float* const l_o  = g_o  + (size_t)NB*NT*NH;
  float* const r_o  = l_o  + (size_t)NB*NT*NH;

  float myh = 0.f;   // this lane's own h_prev (register)

  for (int t = 0; t < NT; ++t) {
    // ---- stage x_t ----
    #pragma unroll
    for (int i = 0; i < 2; ++i) {
      const int f4 = tid + i*256;
      const int bb = f4 >> 6;
      const int d4 = f4 & 63;
      *(float4*)(&x_lds[bb][d4*4]) =
        *(const float4*)(x + ((size_t)(b_base+bb)*NT + t)*ND + d4*4);
    }
    __syncthreads();

    float rowv = 0.f, gv = 0.f;   // the ONLY state carried across the wait

    // per-b: reduce acc[9] -> 2 scalars, accumulate if b == b_out
    auto finish_b = [&](float* acc, int b) {
      #pragma unroll
      for (int i = 0; i < 9; ++i) acc[i] = rowsum16(acc[i]);
      float sr = acc[0];
      #pragma unroll
      for (int i = 1; i < 8; ++i) sr = (i_out == i) ? acc[i] : sr;
      float sg = acc[8];
      sr = xor_combine(sr);
      sg = xor_combine(sg);
      if (b == b_out) { rowv += sr; gv += sg; }
    };

    // ---- x-part (before the recurrence wait), fully reduced ----
    #pragma unroll
    for (int b = 0; b < 8; ++b) {
      const float4 x4 = *(const float4*)(&x_lds[b][kc*4]);
      float acc[9];
      #pragma unroll
      for (int i = 0; i < 8; ++i)
        acc[i] = wx4[i].x*x4.x + wx4[i].y*x4.y + wx4[i].z*x4.z + wx4[i].w*x4.w;
      acc[8] = ws4.x*x4.x + ws4.y*x4.y + ws4.z*x4.z + ws4.w*x4.w;
      finish_b(acc, b);
    }

    // ---- wait for h_{t-1} (LLC poll), stage, h-part ----
    if (t > 0) {
      if (w == 0) {
        const unsigned int* fp = flags + ((size_t)bg*NT + (t-1))*32 + (kc & 31);
        while (true) {
          unsigned int v;
          asm volatile("global_load_dword %0, %1, off sc0 sc1\n\t"
                       "s_waitcnt vmcnt(0)"
                       : "=v"(v) : "v"(fp) : "memory");
          if (__all((int)(v != 0u))) break;
          __builtin_amdgcn_s_sleep(1);
        }
      }
      __syncthreads();
      const float* src = hbuf + ((size_t)((t-1)&1)*NB + b_base)*NH;
      float4 hv[8];
      #pragma unroll
      for (int i = 0; i < 8; ++i) {
        const float* a = src + (size_t)(tid + i*256)*4;
        asm volatile("global_load_dwordx4 %0, %1, off sc0 sc1"
                     : "=v"(hv[i]) : "v"(a) : "memory");
      }
      asm volatile("s_waitcnt vmcnt(0)" ::: "memory");
      __builtin_amdgcn_sched_barrier(0);
      #pragma unroll
      for (int i = 0; i < 8; ++i)
        *(float4*)((float*)h_lds + (size_t)(tid + i*256)*4) = hv[i];
      __syncthreads();

      #pragma unroll
      for (int b = 0; b < 8; ++b) {
        float acc[9];
        #pragma unroll
        for (int i = 0; i < 9; ++i) acc[i] = 0.f;
        #pragma unroll
        for (int j = 0; j < 4; ++j) {
          const float4 h4 = *(const float4*)(&h_lds[b][kc*4 + j*256]);
          #pragma unroll
          for (int i = 0; i < 8; ++i)
            acc[i] += wh[i][j].x*h4.x + wh[i][j].y*h4.y +
                      wh[i][j].z*h4.z + wh[i][j].w*h4.w;
          acc[8] += us4[j].x*h4.x + us4[j].y*h4.y + us4[j].z*h4.z + us4[j].w*h4.w;
        }
        finish_b(acc, b);
      }
    }

    // ---- epilogue: one (batch,row) output per lane ----
    const float sg   = 1.f / (1.f + expf(-(gv + wsb)));
    const float pre  = rowv + wxb_r;
    const float htld = tanhf(pre);
    const float hp   = myh;
    const float h    = (1.f - sg)*hp + sg*htld;
    myh = h;
    {
      float* hptr = hbuf + ((size_t)(t & 1)*NB + (b_base + b_out))*NH + rg_out;
      asm volatile("global_store_dword %0, %1, off sc0 sc1"
                   :: "v"(hptr), "v"(h) : "memory");
    }
    __syncthreads();     // drains vmcnt(0): all h stores at LLC before flag
    if (tid == 0) {
      unsigned int one = 1u;
      unsigned int* fp = flags + ((size_t)bg*NT + t)*32 + sl;
      asm volatile("global_store_dword %0, %1, off sc0 sc1"
                   :: "v"(fp), "v"(one) : "memory");
    }

    // ---- outputs (post-signal, off critical path) ----
    {
      const size_t obase = ((size_t)(b_base + b_out)*NT + t)*NH + rg_out;
      const float sp = sg * (1.f - sg);
      __builtin_nontemporal_store(h, &hs_o[obase]);
      __builtin_nontemporal_store(sg, &g_o[obase]);
      __builtin_nontemporal_store(1.f - sg, &l_o[obase]);
      __builtin_nontemporal_store((htld - hp)*(sp*usr_r) + sg*(1.f - htld*htld)*whd_r,
                                  &r_o[obase]);
    }
  }
}

// ys[b,t] = out_w . hs[b,t,:] + out_b
__global__ void yfinish_kernel(const float* __restrict__ hs,
                               const float* __restrict__ out_w,
                               const float* __restrict__ out_b,
                               float* __restrict__ ys)
{
  const int row  = (int)blockIdx.x*4 + ((int)threadIdx.x >> 6);
  const int lane = (int)threadIdx.x & 63;
  const float4* hp = (const float4*)(hs + (size_t)row*NH);
  const float4* wp = (const float4*)out_w;
  float s = 0.f;
  #pragma unroll
  for (int i = 0; i < 4; ++i) {
    const float4 h4 = hp[i*64 + lane];
    const float4 w4 = wp[i*64 + lane];
    s += h4.x*w4.x + h4.y*w4.y + h4.z*w4.z + h4.w*w4.w;
  }
  #pragma unroll
  for (int off = 32; off > 0; off >>= 1) s += __shfl_xor(s, off, 64);
  if (lane == 0) ys[row] = s + out_b[0];
}

extern "C" void kernel_launch(void* const* d_in, const int* in_sizes, int n_in,
                              void* d_out, int out_size, void* d_ws, size_t ws_size,
                              hipStream_t stream)
{
  (void)in_sizes; (void)n_in; (void)out_size; (void)ws_size;
  const float* x     = (const float*)d_in[0];
  const float* Wx_w  = (const float*)d_in[1];
  const float* Wx_b  = (const float*)d_in[2];
  const float* Wh_w  = (const float*)d_in[3];
  const float* Ws_w  = (const float*)d_in[4];
  const float* Ws_b  = (const float*)d_in[5];
  const float* Us_w  = (const float*)d_in[6];
  const float* out_w = (const float*)d_in[7];
  const float* out_b = (const float*)d_in[8];
  float* out = (float*)d_out;

  char* ws = (char*)d_ws;
  float* hbuf = (float*)ws;                                      // 512 KB
  unsigned int* flags = (unsigned int*)(ws + (size_t)2*NB*NH*4); // 512 KB

  hipMemsetAsync(flags, 0, (size_t)8*NT*32*sizeof(unsigned int), stream);
  rnn_step_kernel<<<dim3(256), dim3(256), 0, stream>>>(
      x, Wx_w, Wx_b, Wh_w, Ws_w, Ws_b, Us_w, out, hbuf, flags);
  yfinish_kernel<<<dim3((NB*NT)/4), dim3(256), 0, stream>>>(
      out + (size_t)NB*NT, out_w, out_b, out);
}

// Round 6
// 2065.088 us; speedup vs baseline: 10.3900x; 1.7857x over previous
//
#include <hip/hip_runtime.h>

#define NT 512
#define ND 256
#define NH 1024
#define NB 64
// R6 = R5 (MFMA restructure) with the x-staging bug fixed (was staging 64/256
// elements per batch; x-MFMA read garbage chunks 8..31).
// Grid 256 wgs = 4 batch-groups(16 batches) x 64 slices(16 rows).
// Per step per wg: C[16 rows][16 batches] = Wh_slice @ h^T (K=1024, 8 mfma/wave)
//                                         + Wx_slice @ x^T (K=256, 2 mfma/wave),
// K split across 4 waves, partials summed in LDS. Gate (Us.h + Ws.x) on VALU
// from the same B-fragments, reduced via shfl + LDS. h handoff at LLC scope
// (sc0 sc1) as bf16. Flag protocol identical to R4 (proven).

typedef float f32x4 __attribute__((ext_vector_type(4)));
typedef short bf16x8 __attribute__((ext_vector_type(8)));

__device__ __forceinline__ unsigned short f2bf(float f) {     // RNE
  unsigned u = __builtin_bit_cast(unsigned, f);
  u += 0x7fffu + ((u >> 16) & 1u);
  return (unsigned short)(u >> 16);
}
__device__ __forceinline__ float bflo(unsigned u) {
  return __builtin_bit_cast(float, u << 16);
}
__device__ __forceinline__ float bfhi(unsigned u) {
  return __builtin_bit_cast(float, u & 0xffff0000u);
}
__device__ __forceinline__ bf16x8 pack8(float4 a, float4 b) {
  bf16x8 r;
  r[0] = (short)f2bf(a.x); r[1] = (short)f2bf(a.y);
  r[2] = (short)f2bf(a.z); r[3] = (short)f2bf(a.w);
  r[4] = (short)f2bf(b.x); r[5] = (short)f2bf(b.y);
  r[6] = (short)f2bf(b.z); r[7] = (short)f2bf(b.w);
  return r;
}

__global__ void __launch_bounds__(256, 1)
rnn_step_kernel(const float* __restrict__ x,
                const float* __restrict__ Wx_w,
                const float* __restrict__ Wx_b,
                const float* __restrict__ Wh_w,
                const float* __restrict__ Ws_w,
                const float* __restrict__ Ws_b,
                const float* __restrict__ Us_w,
                float* __restrict__ out,
                unsigned short* __restrict__ hbuf,   // bf16 [2][NB][NH]
                unsigned int* __restrict__ flags)    // [4][NT][64]
{
  const int tid = (int)threadIdx.x;
  const int w   = tid >> 6;        // wave
  const int l   = tid & 63;        // lane
  const int bm  = l & 15;          // mfma row/col index for A/B frags
  const int lg  = l >> 4;          // lane group
  const int sl  = (int)blockIdx.x & 63;
  const int bg  = (int)blockIdx.x >> 6;
  const int r_base = sl * 16;
  const int b_base = bg * 16;
  // epilogue ownership: thread -> (row ro, batch bo); one output each
  const int bo = tid & 15;
  const int ro = tid >> 4;
  const int rg = r_base + ro;
  const int b_glob = b_base + bo;

  __shared__ unsigned short h_sh[16][1024];   // 32 KB, 16B-chunk XOR swizzled
  __shared__ unsigned short x_sh[16][256];    // 8 KB, same swizzle
  __shared__ unsigned short us_sh[1024];      // 2 KB, linear
  __shared__ unsigned short ws_sh[256];       // 0.5 KB, linear
  __shared__ float cpart[4][4][64];           // per-wave C partials
  __shared__ float gpart[4][16];              // per-wave gate partials

  // ---- one-time staging: Us/Ws to bf16 LDS ----
  {
    const float4 uv = *(const float4*)(Us_w + tid*4);
    us_sh[tid*4+0] = f2bf(uv.x); us_sh[tid*4+1] = f2bf(uv.y);
    us_sh[tid*4+2] = f2bf(uv.z); us_sh[tid*4+3] = f2bf(uv.w);
    if (tid < 64) {
      const float4 wv = *(const float4*)(Ws_w + tid*4);
      ws_sh[tid*4+0] = f2bf(wv.x); ws_sh[tid*4+1] = f2bf(wv.y);
      ws_sh[tid*4+2] = f2bf(wv.z); ws_sh[tid*4+3] = f2bf(wv.w);
    }
  }

  // ---- A-fragments in registers (bf16), held all 512 steps ----
  // A layout (m89-verified): row = l&15, k = ktile + (l>>4)*8 + j
  bf16x8 whf[8];   // wave w covers h-K slice [w*256, w*256+256) -> 8 mfma
  bf16x8 wxf[2];   // wave w covers x-K slice [w*64, w*64+64)    -> 2 mfma
  {
    const int ar = r_base + bm;
    #pragma unroll
    for (int m = 0; m < 8; ++m) {
      const int k0 = w*256 + m*32 + lg*8;
      const float4 f0 = *(const float4*)(Wh_w + (size_t)ar*NH + k0);
      const float4 f1 = *(const float4*)(Wh_w + (size_t)ar*NH + k0 + 4);
      whf[m] = pack8(f0, f1);
    }
    #pragma unroll
    for (int m = 0; m < 2; ++m) {
      const int k0 = w*64 + m*32 + lg*8;
      const float4 f0 = *(const float4*)(Wx_w + (size_t)ar*ND + k0);
      const float4 f1 = *(const float4*)(Wx_w + (size_t)ar*ND + k0 + 4);
      wxf[m] = pack8(f0, f1);
    }
  }
  // per-thread epilogue constants (fp32, exact)
  const float wxb_r = Wx_b[rg];
  const float whd_r = Wh_w[(size_t)rg*NH + rg];
  const float usr_r = Us_w[rg];
  const float wsb   = Ws_b[0];

  float* const hs_o = out + (size_t)NB*NT;
  float* const g_o  = hs_o + (size_t)NB*NT*NH;
  float* const l_o  = g_o  + (size_t)NB*NT*NH;
  float* const rd_o = l_o  + (size_t)NB*NT*NH;

  float myh = 0.f;

  for (int t = 0; t < NT; ++t) {
    // ---- stage x_t -> bf16 LDS (swizzled); FULL 256 elems/batch (R5 bug fix) ----
    #pragma unroll
    for (int it = 0; it < 4; ++it) {
      const int f4 = tid + it*256;         // 0..1023
      const int b  = f4 >> 6;              // 0..15
      const int d4 = f4 & 63;              // 0..63 float4-chunks of 4
      const float4 xv = *(const float4*)(x + ((size_t)(b_base+b)*NT + t)*ND + d4*4);
      const int c = (d4 >> 1) ^ (b & 7);   // 8-bf16 chunk 0..31, swizzled
      const unsigned p0 = (unsigned)f2bf(xv.x) | ((unsigned)f2bf(xv.y) << 16);
      const unsigned p1 = (unsigned)f2bf(xv.z) | ((unsigned)f2bf(xv.w) << 16);
      *(uint2*)&x_sh[b][c*8 + (d4 & 1)*4] = make_uint2(p0, p1);
    }
    __syncthreads();

    // ---- x-part: 2 mfma + gate-x VALU (all before the recurrence wait) ----
    f32x4 acc = {0.f, 0.f, 0.f, 0.f};
    float ga = 0.f;
    #pragma unroll
    for (int m = 0; m < 2; ++m) {
      const int c0 = (w*8 + m*4 + lg) ^ (bm & 7);
      const uint4 bxu = *(const uint4*)&x_sh[bm][c0*8];
      acc = __builtin_amdgcn_mfma_f32_16x16x32_bf16(
              wxf[m], __builtin_bit_cast(bf16x8, bxu), acc, 0, 0, 0);
      const int ku = w*64 + m*32 + lg*8;
      const uint4 uu = *(const uint4*)&ws_sh[ku];
      ga += bflo(uu.x)*bflo(bxu.x) + bfhi(uu.x)*bfhi(bxu.x);
      ga += bflo(uu.y)*bflo(bxu.y) + bfhi(uu.y)*bfhi(bxu.y);
      ga += bflo(uu.z)*bflo(bxu.z) + bfhi(uu.z)*bfhi(bxu.z);
      ga += bflo(uu.w)*bflo(bxu.w) + bfhi(uu.w)*bfhi(bxu.w);
    }

    // ---- wait for h_{t-1} (LLC poll), stage bf16 -> LDS, h-part mfma ----
    if (t > 0) {
      if (w == 0) {
        const unsigned int* fp = flags + ((size_t)bg*NT + (t-1))*64 + l;
        while (true) {
          unsigned int v;
          asm volatile("global_load_dword %0, %1, off sc0 sc1\n\t"
                       "s_waitcnt vmcnt(0)"
                       : "=v"(v) : "v"(fp) : "memory");
          if (__all((int)(v != 0u))) break;
          __builtin_amdgcn_s_sleep(1);
        }
      }
      __syncthreads();
      {
        const unsigned short* src = hbuf + ((size_t)((t-1)&1)*NB + b_base)*NH;
        uint4 hv[8];
        #pragma unroll
        for (int it = 0; it < 8; ++it) {
          const int f4 = tid + it*256;
          const unsigned short* a = src + (size_t)(f4 >> 7)*NH + (f4 & 127)*8;
          asm volatile("global_load_dwordx4 %0, %1, off sc0 sc1"
                       : "=v"(hv[it]) : "v"(a) : "memory");
        }
        asm volatile("s_waitcnt vmcnt(0)" ::: "memory");
        __builtin_amdgcn_sched_barrier(0);
        #pragma unroll
        for (int it = 0; it < 8; ++it) {
          const int f4 = tid + it*256;
          const int b = f4 >> 7, c = f4 & 127;
          *(uint4*)&h_sh[b][(c ^ (b & 7))*8] = hv[it];
        }
      }
      __syncthreads();

      #pragma unroll
      for (int m = 0; m < 8; ++m) {
        const int c0 = (w*32 + m*4 + lg) ^ (bm & 7);
        const uint4 bhu = *(const uint4*)&h_sh[bm][c0*8];
        acc = __builtin_amdgcn_mfma_f32_16x16x32_bf16(
                whf[m], __builtin_bit_cast(bf16x8, bhu), acc, 0, 0, 0);
        const int ku = w*256 + m*32 + lg*8;
        const uint4 uu = *(const uint4*)&us_sh[ku];
        ga += bflo(uu.x)*bflo(bhu.x) + bfhi(uu.x)*bfhi(bhu.x);
        ga += bflo(uu.y)*bflo(bhu.y) + bfhi(uu.y)*bfhi(bhu.y);
        ga += bflo(uu.z)*bflo(bhu.z) + bfhi(uu.z)*bfhi(bhu.z);
        ga += bflo(uu.w)*bflo(bhu.w) + bfhi(uu.w)*bfhi(bhu.w);
      }
    }

    // ---- combine partials: gate over lane-groups (shfl) + waves (LDS) ----
    ga += __shfl_xor(ga, 16, 64);
    ga += __shfl_xor(ga, 32, 64);
    if (l < 16) gpart[w][l] = ga;
    cpart[w][0][l] = acc[0];
    cpart[w][1][l] = acc[1];
    cpart[w][2][l] = acc[2];
    cpart[w][3][l] = acc[3];
    __syncthreads();

    // ---- epilogue: 1 output per thread (row ro, batch bo) ----
    // C mapping (m89): col=lane&15, row=(lane>>4)*4+reg
    const float gsum = gpart[0][bo] + gpart[1][bo] + gpart[2][bo] + gpart[3][bo];
    const int ci = ro & 3, cl = (ro >> 2)*16 + bo;
    const float pre0 = cpart[0][ci][cl] + cpart[1][ci][cl] +
                       cpart[2][ci][cl] + cpart[3][ci][cl];
    const float sg   = 1.f / (1.f + expf(-(gsum + wsb)));
    const float pre  = pre0 + wxb_r;
    const float htld = tanhf(pre);
    const float hp   = myh;
    const float h    = (1.f - sg)*hp + sg*htld;
    myh = h;
    {
      const unsigned hb = (unsigned)f2bf(h);
      unsigned short* hp2 = hbuf + ((size_t)(t & 1)*NB + b_glob)*NH + rg;
      asm volatile("global_store_short %0, %1, off sc0 sc1"
                   :: "v"(hp2), "v"(hb) : "memory");
    }
    asm volatile("s_waitcnt vmcnt(0)" ::: "memory");
    __syncthreads();     // all h stores at LLC before flag
    if (tid == 0) {
      unsigned int one = 1u;
      unsigned int* fp = flags + ((size_t)bg*NT + t)*64 + sl;
      asm volatile("global_store_dword %0, %1, off sc0 sc1"
                   :: "v"(fp), "v"(one) : "memory");
    }

    // ---- outputs (post-signal, off critical path) ----
    {
      const size_t obase = ((size_t)b_glob*NT + t)*NH + rg;
      const float sp = sg * (1.f - sg);
      __builtin_nontemporal_store(h, &hs_o[obase]);
      __builtin_nontemporal_store(sg, &g_o[obase]);
      __builtin_nontemporal_store(1.f - sg, &l_o[obase]);
      __builtin_nontemporal_store((htld - hp)*(sp*usr_r) + sg*(1.f - htld*htld)*whd_r,
                                  &rd_o[obase]);
    }
  }
}

// ys[b,t] = out_w . hs[b,t,:] + out_b
__global__ void yfinish_kernel(const float* __restrict__ hs,
                               const float* __restrict__ out_w,
                               const float* __restrict__ out_b,
                               float* __restrict__ ys)
{
  const int row  = (int)blockIdx.x*4 + ((int)threadIdx.x >> 6);
  const int lane = (int)threadIdx.x & 63;
  const float4* hp = (const float4*)(hs + (size_t)row*NH);
  const float4* wp = (const float4*)out_w;
  float s = 0.f;
  #pragma unroll
  for (int i = 0; i < 4; ++i) {
    const float4 h4 = hp[i*64 + lane];
    const float4 w4 = wp[i*64 + lane];
    s += h4.x*w4.x + h4.y*w4.y + h4.z*w4.z + h4.w*w4.w;
  }
  #pragma unroll
  for (int off = 32; off > 0; off >>= 1) s += __shfl_xor(s, off, 64);
  if (lane == 0) ys[row] = s + out_b[0];
}

extern "C" void kernel_launch(void* const* d_in, const int* in_sizes, int n_in,
                              void* d_out, int out_size, void* d_ws, size_t ws_size,
                              hipStream_t stream)
{
  (void)in_sizes; (void)n_in; (void)out_size; (void)ws_size;
  const float* x     = (const float*)d_in[0];
  const float* Wx_w  = (const float*)d_in[1];
  const float* Wx_b  = (const float*)d_in[2];
  const float* Wh_w  = (const float*)d_in[3];
  const float* Ws_w  = (const float*)d_in[4];
  const float* Ws_b  = (const float*)d_in[5];
  const float* Us_w  = (const float*)d_in[6];
  const float* out_w = (const float*)d_in[7];
  const float* out_b = (const float*)d_in[8];
  float* out = (float*)d_out;

  char* ws = (char*)d_ws;
  unsigned short* hbuf = (unsigned short*)ws;                 // bf16, 256 KB
  unsigned int* flags  = (unsigned int*)(ws + 262144);        // 512 KB

  hipMemsetAsync(flags, 0, (size_t)4*NT*64*sizeof(unsigned int), stream);
  rnn_step_kernel<<<dim3(256), dim3(256), 0, stream>>>(
      x, Wx_w, Wx_b, Wh_w, Ws_w, Ws_b, Us_w, out, hbuf, flags);
  yfinish_kernel<<<dim3((NB*NT)/4), dim3(256), 0, stream>>>(
      out + (size_t)NB*NT, out_w, out_b, out);
}

// Round 7
// 1833.811 us; speedup vs baseline: 11.7003x; 1.1261x over previous
//
#include <hip/hip_runtime.h>

#define NT 512
#define ND 256
#define NH 1024
#define NB 64
// R7: staging-free MFMA RNN.
// Grid 256 wgs = 4 batch-groups(16 batches) x 64 slices(16 rows); block = 4 waves.
// Per step per wg: C[16 rows][16 batches] = Wh_slice @ h^T (K=1024) + Wx_slice @ x^T
// (K=256), K split across 4 waves. B-fragments loaded DIRECTLY from global
// (h: sc0 sc1 LLC; x: cached f32 + in-reg bf16 pack) — no LDS staging, 2 barriers/step.
// Epilogue ownership ro=tid&15 -> full-64B-line output writes.
// h handoff at LLC scope (sc0 sc1) with per-slice flags (protocol proven R2-R6).

typedef float f32x4 __attribute__((ext_vector_type(4)));
typedef short bf16x8 __attribute__((ext_vector_type(8)));

__device__ __forceinline__ unsigned short f2bf(float f) {     // RNE
  unsigned u = __builtin_bit_cast(unsigned, f);
  u += 0x7fffu + ((u >> 16) & 1u);
  return (unsigned short)(u >> 16);
}
__device__ __forceinline__ float bflo(unsigned u) {
  return __builtin_bit_cast(float, u << 16);
}
__device__ __forceinline__ float bfhi(unsigned u) {
  return __builtin_bit_cast(float, u & 0xffff0000u);
}
__device__ __forceinline__ bf16x8 pack8(float4 a, float4 b) {
  bf16x8 r;
  r[0] = (short)f2bf(a.x); r[1] = (short)f2bf(a.y);
  r[2] = (short)f2bf(a.z); r[3] = (short)f2bf(a.w);
  r[4] = (short)f2bf(b.x); r[5] = (short)f2bf(b.y);
  r[6] = (short)f2bf(b.z); r[7] = (short)f2bf(b.w);
  return r;
}

__global__ void __launch_bounds__(256, 1)
rnn_step_kernel(const float* __restrict__ x,
                const float* __restrict__ Wx_w,
                const float* __restrict__ Wx_b,
                const float* __restrict__ Wh_w,
                const float* __restrict__ Ws_w,
                const float* __restrict__ Ws_b,
                const float* __restrict__ Us_w,
                float* __restrict__ out,
                unsigned short* __restrict__ hbuf,   // bf16 [2][NB][NH]
                unsigned int* __restrict__ flags)    // [4][NT][64]
{
  const int tid = (int)threadIdx.x;
  const int w   = tid >> 6;        // wave
  const int l   = tid & 63;        // lane
  const int bm  = l & 15;          // mfma row/col index for A/B frags
  const int lg  = l >> 4;          // lane group
  const int sl  = (int)blockIdx.x & 63;
  const int bg  = (int)blockIdx.x >> 6;
  const int r_base = sl * 16;
  const int b_base = bg * 16;
  // epilogue ownership: ro = tid&15 (consecutive lanes -> consecutive rows)
  const int ro = tid & 15;
  const int bo = tid >> 4;
  const int rg = r_base + ro;
  const int b_glob = b_base + bo;

  __shared__ unsigned short us_sh[1024];   // bf16 Us (broadcast reads)
  __shared__ float cpart[4][4][72];        // per-wave C partials, padded
  __shared__ float gpart[4][16];           // per-wave gate partials

  // ---- one-time: Us -> bf16 LDS ----
  {
    const float4 uv = *(const float4*)(Us_w + tid*4);
    us_sh[tid*4+0] = f2bf(uv.x); us_sh[tid*4+1] = f2bf(uv.y);
    us_sh[tid*4+2] = f2bf(uv.z); us_sh[tid*4+3] = f2bf(uv.w);
  }

  // ---- A-fragments in registers (bf16), held all 512 steps ----
  // A layout (m89): row = l&15, k = ktile + (l>>4)*8 + j
  bf16x8 whf[8];   // wave w: h-K slice [w*256, w*256+256) -> 8 mfma
  bf16x8 wxf[2];   // wave w: x-K slice [w*64, w*64+64)    -> 2 mfma
  float4 wsf[4];   // Ws f32 slice for gate-x (exact f32 math)
  {
    const int ar = r_base + bm;
    #pragma unroll
    for (int m = 0; m < 8; ++m) {
      const int k0 = w*256 + m*32 + lg*8;
      const float4 f0 = *(const float4*)(Wh_w + (size_t)ar*NH + k0);
      const float4 f1 = *(const float4*)(Wh_w + (size_t)ar*NH + k0 + 4);
      whf[m] = pack8(f0, f1);
    }
    #pragma unroll
    for (int m = 0; m < 2; ++m) {
      const int k0 = w*64 + m*32 + lg*8;
      const float4 f0 = *(const float4*)(Wx_w + (size_t)ar*ND + k0);
      const float4 f1 = *(const float4*)(Wx_w + (size_t)ar*ND + k0 + 4);
      wxf[m] = pack8(f0, f1);
      wsf[m*2]   = *(const float4*)(Ws_w + k0);
      wsf[m*2+1] = *(const float4*)(Ws_w + k0 + 4);
    }
  }
  // per-thread epilogue constants (fp32, exact)
  const float wxb_r = Wx_b[rg];
  const float whd_r = Wh_w[(size_t)rg*NH + rg];
  const float usr_r = Us_w[rg];
  const float wsb   = Ws_b[0];

  float* const hs_o = out + (size_t)NB*NT;
  float* const g_o  = hs_o + (size_t)NB*NT*NH;
  float* const l_o  = g_o  + (size_t)NB*NT*NH;
  float* const rd_o = l_o  + (size_t)NB*NT*NH;

  __syncthreads();

  float myh = 0.f;

  for (int t = 0; t < NT; ++t) {
    // ---- x-part: direct f32 loads, in-reg pack, 2 mfma + gate-x (f32) ----
    f32x4 acc = {0.f, 0.f, 0.f, 0.f};
    float ga = 0.f;
    {
      const float* xrow = x + ((size_t)(b_base+bm)*NT + t)*ND + w*64 + lg*8;
      #pragma unroll
      for (int m = 0; m < 2; ++m) {
        const float4 f0 = *(const float4*)(xrow + m*32);
        const float4 f1 = *(const float4*)(xrow + m*32 + 4);
        acc = __builtin_amdgcn_mfma_f32_16x16x32_bf16(
                wxf[m], pack8(f0, f1), acc, 0, 0, 0);
        ga += wsf[m*2].x*f0.x + wsf[m*2].y*f0.y + wsf[m*2].z*f0.z + wsf[m*2].w*f0.w
            + wsf[m*2+1].x*f1.x + wsf[m*2+1].y*f1.y + wsf[m*2+1].z*f1.z + wsf[m*2+1].w*f1.w;
      }
    }

    // ---- wait for h_{t-1} (all waves poll), direct B-frag loads, h mfma ----
    if (t > 0) {
      {
        const unsigned int* fp = flags + ((size_t)bg*NT + (t-1))*64 + l;
        while (true) {
          unsigned int v;
          asm volatile("global_load_dword %0, %1, off sc0 sc1\n\t"
                       "s_waitcnt vmcnt(0)"
                       : "=v"(v) : "v"(fp) : "memory");
          if (__all((int)(v != 0u))) break;
          __builtin_amdgcn_s_sleep(1);
        }
      }
      const unsigned short* hrow =
          hbuf + ((size_t)((t-1)&1)*NB + b_base + bm)*NH + w*256 + lg*8;
      uint4 hv[8];
      #pragma unroll
      for (int m = 0; m < 8; ++m)
        asm volatile("global_load_dwordx4 %0, %1, off sc0 sc1"
                     : "=v"(hv[m]) : "v"(hrow + m*32) : "memory");
      asm volatile("s_waitcnt vmcnt(0)" ::: "memory");
      __builtin_amdgcn_sched_barrier(0);
      #pragma unroll
      for (int m = 0; m < 8; ++m) {
        acc = __builtin_amdgcn_mfma_f32_16x16x32_bf16(
                whf[m], __builtin_bit_cast(bf16x8, hv[m]), acc, 0, 0, 0);
        const uint4 uu = *(const uint4*)&us_sh[w*256 + m*32 + lg*8];
        ga += bflo(uu.x)*bflo(hv[m].x) + bfhi(uu.x)*bfhi(hv[m].x)
            + bflo(uu.y)*bflo(hv[m].y) + bfhi(uu.y)*bfhi(hv[m].y)
            + bflo(uu.z)*bflo(hv[m].z) + bfhi(uu.z)*bfhi(hv[m].z)
            + bflo(uu.w)*bflo(hv[m].w) + bfhi(uu.w)*bfhi(hv[m].w);
      }
    }

    // ---- combine partials ----
    ga += __shfl_xor(ga, 16, 64);
    ga += __shfl_xor(ga, 32, 64);
    if (l < 16) gpart[w][l] = ga;      // lane bm holds batch bm's partial
    cpart[w][0][l] = acc[0];
    cpart[w][1][l] = acc[1];
    cpart[w][2][l] = acc[2];
    cpart[w][3][l] = acc[3];
    __syncthreads();                   // barrier (a)

    // ---- epilogue: 1 output per thread (row ro, batch bo) ----
    // C mapping (m89): col(lane&15)=batch, row=(lane>>4)*4+reg
    const float gsum = gpart[0][bo] + gpart[1][bo] + gpart[2][bo] + gpart[3][bo];
    const int ci = ro & 3, cl = ((ro >> 2) << 4) + bo;
    const float pre0 = cpart[0][ci][cl] + cpart[1][ci][cl] +
                       cpart[2][ci][cl] + cpart[3][ci][cl];
    const float sg   = 1.f / (1.f + expf(-(gsum + wsb)));
    const float pre  = pre0 + wxb_r;
    const float htld = tanhf(pre);
    const float hp   = myh;
    const float h    = (1.f - sg)*hp + sg*htld;
    myh = h;
    {
      const unsigned hb = (unsigned)f2bf(h);
      unsigned short* hptr = hbuf + ((size_t)(t & 1)*NB + b_glob)*NH + rg;
      asm volatile("global_store_short %0, %1, off sc0 sc1"
                   :: "v"(hptr), "v"(hb) : "memory");
    }
    asm volatile("s_waitcnt vmcnt(0)" ::: "memory");
    __syncthreads();                   // barrier (b): all h stores at LLC
    if (tid == 0) {
      unsigned int one = 1u;
      unsigned int* fp = flags + ((size_t)bg*NT + t)*64 + sl;
      asm volatile("global_store_dword %0, %1, off sc0 sc1"
                   :: "v"(fp), "v"(one) : "memory");
    }

    // ---- outputs (post-signal; lanes 0-15 write consecutive f32 -> full lines) ----
    {
      const size_t obase = ((size_t)b_glob*NT + t)*NH + rg;
      const float sp = sg * (1.f - sg);
      __builtin_nontemporal_store(h, &hs_o[obase]);
      __builtin_nontemporal_store(sg, &g_o[obase]);
      __builtin_nontemporal_store(1.f - sg, &l_o[obase]);
      __builtin_nontemporal_store((htld - hp)*(sp*usr_r) + sg*(1.f - htld*htld)*whd_r,
                                  &rd_o[obase]);
    }
  }
}

// ys[b,t] = out_w . hs[b,t,:] + out_b
__global__ void yfinish_kernel(const float* __restrict__ hs,
                               const float* __restrict__ out_w,
                               const float* __restrict__ out_b,
                               float* __restrict__ ys)
{
  const int row  = (int)blockIdx.x*4 + ((int)threadIdx.x >> 6);
  const int lane = (int)threadIdx.x & 63;
  const float4* hp = (const float4*)(hs + (size_t)row*NH);
  const float4* wp = (const float4*)out_w;
  float s = 0.f;
  #pragma unroll
  for (int i = 0; i < 4; ++i) {
    const float4 h4 = hp[i*64 + lane];
    const float4 w4 = wp[i*64 + lane];
    s += h4.x*w4.x + h4.y*w4.y + h4.z*w4.z + h4.w*w4.w;
  }
  #pragma unroll
  for (int off = 32; off > 0; off >>= 1) s += __shfl_xor(s, off, 64);
  if (lane == 0) ys[row] = s + out_b[0];
}

extern "C" void kernel_launch(void* const* d_in, const int* in_sizes, int n_in,
                              void* d_out, int out_size, void* d_ws, size_t ws_size,
                              hipStream_t stream)
{
  (void)in_sizes; (void)n_in; (void)out_size; (void)ws_size;
  const float* x     = (const float*)d_in[0];
  const float* Wx_w  = (const float*)d_in[1];
  const float* Wx_b  = (const float*)d_in[2];
  const float* Wh_w  = (const float*)d_in[3];
  const float* Ws_w  = (const float*)d_in[4];
  const float* Ws_b  = (const float*)d_in[5];
  const float* Us_w  = (const float*)d_in[6];
  const float* out_w = (const float*)d_in[7];
  const float* out_b = (const float*)d_in[8];
  float* out = (float*)d_out;

  char* ws = (char*)d_ws;
  unsigned short* hbuf = (unsigned short*)ws;                 // bf16, 256 KB
  unsigned int* flags  = (unsigned int*)(ws + 262144);        // 512 KB

  hipMemsetAsync(flags, 0, (size_t)4*NT*64*sizeof(unsigned int), stream);
  rnn_step_kernel<<<dim3(256), dim3(256), 0, stream>>>(
      x, Wx_w, Wx_b, Wh_w, Ws_w, Ws_b, Us_w, out, hbuf, flags);
  yfinish_kernel<<<dim3((NB*NT)/4), dim3(256), 0, stream>>>(
      out + (size_t)NB*NT, out_w, out_b, out);
}